// Round 4
// baseline (340.455 us; speedup 1.0000x reference)
//
#include <hip/hip_runtime.h>
#include <hip/hip_bf16.h>
#include <math.h>

#define BSZ 8
#define LQ  1024
#define LV  13294
#define NH  8
#define HD  32
#define VM  (BSZ * LV)   // 106352 rows of value

typedef __attribute__((ext_vector_type(8))) short bf16x8;
typedef __attribute__((ext_vector_type(4))) float f32x4;

__device__ static inline unsigned short f2bf(float f) {
    unsigned int u = __float_as_uint(f);
    unsigned int r = (u + 0x7FFFu + ((u >> 16) & 1u)) >> 16;
    return (unsigned short)r;
}
__device__ static inline float bf2f(unsigned short s) {
    return __uint_as_float(((unsigned int)s) << 16);
}
// pack two f32 -> one dword of 2 bf16 (RNE), hopefully v_cvt_pk_bf16_f32
__device__ static inline unsigned int pk2bf(float a, float b) {
    __hip_bfloat162 h = __float22bfloat162_rn(make_float2(a, b));
    return *(unsigned int*)&h;
}

union BF8 { unsigned int u[4]; bf16x8 v; };

// ---------------------------------------------------------------------------
// Transpose+convert vp_w and op_w [k][n] f32 -> [n][k] bf16. Grid 512.
// ---------------------------------------------------------------------------
__global__ __launch_bounds__(256) void wconv_kernel(
    const float* __restrict__ w0, const float* __restrict__ w1,
    unsigned short* __restrict__ t0, unsigned short* __restrict__ t1)
{
    const int n = blockIdx.x & 255;
    const int k = threadIdx.x;
    if (blockIdx.x < 256) t0[n * 256 + k] = f2bf(w0[k * 256 + n]);
    else                  t1[n * 256 + k] = f2bf(w1[k * 256 + n]);
}

// ---------------------------------------------------------------------------
// vproj v3: v = value @ vp_w + vp_b -> [b][h][pix][c] bf16.
// Barrier-free, LDS-free. 512 threads = 8 waves; wave w == head w (32 cols).
// Swapped MFMA operands => acc holds D^T: lane = pix, regs = 4 channels.
// ---------------------------------------------------------------------------
__global__ __launch_bounds__(512, 2) void vproj_mfma_kernel(
    const float* __restrict__ A,            // [VM][256] f32
    const unsigned short* __restrict__ wT,  // [256][256] bf16 [n][k]
    const float* __restrict__ bias,         // [256]
    unsigned short* __restrict__ v)         // [B][H][LV][32] bf16
{
    const int tid  = threadIdx.x;
    const int w    = tid >> 6;        // wave == head, cols w*32..+32
    const int lane = tid & 63;
    const int mrow = lane & 15;
    const int quad = lane >> 4;
    const int m0   = blockIdx.x * 64;

    // W fragments (A-operand role): n = w*32 + j*16 + mrow, k = kc*32+quad*8
    bf16x8 wf[2][8];
#pragma unroll
    for (int j = 0; j < 2; ++j) {
        const int n = w * 32 + j * 16 + mrow;
#pragma unroll
        for (int kc = 0; kc < 8; ++kc)
            wf[j][kc] = *(const bf16x8*)(const void*)(wT + (size_t)n * 256 + kc * 32 + quad * 8);
    }
    float4 bj[2];
#pragma unroll
    for (int j = 0; j < 2; ++j)
        bj[j] = *(const float4*)(bias + w * 32 + j * 16 + quad * 4);

    f32x4 acc[4][2];
#pragma unroll
    for (int i = 0; i < 4; ++i)
#pragma unroll
        for (int j = 0; j < 2; ++j) acc[i][j] = (f32x4)0.f;

#pragma unroll
    for (int kc = 0; kc < 8; ++kc) {
        bf16x8 vf[4];
#pragma unroll
        for (int i = 0; i < 4; ++i) {
            int gm = m0 + i * 16 + mrow;
            gm = (gm < VM) ? gm : (VM - 1);       // clamp tail: loads stay valid
            const float* ap = A + (size_t)gm * 256 + kc * 32 + quad * 8;
            const float4 f0 = *(const float4*)(ap);
            const float4 f1 = *(const float4*)(ap + 4);
            BF8 t;
            t.u[0] = pk2bf(f0.x, f0.y);
            t.u[1] = pk2bf(f0.z, f0.w);
            t.u[2] = pk2bf(f1.x, f1.y);
            t.u[3] = pk2bf(f1.z, f1.w);
            vf[i] = t.v;
        }
#pragma unroll
        for (int i = 0; i < 4; ++i)
#pragma unroll
            for (int j = 0; j < 2; ++j)
                acc[i][j] = __builtin_amdgcn_mfma_f32_16x16x32_bf16(
                    wf[j][kc], vf[i], acc[i][j], 0, 0, 0);
    }

    // epilogue: lane holds pix = m0+i*16+mrow, channels j*16+quad*4 .. +4
#pragma unroll
    for (int i = 0; i < 4; ++i) {
        const int gm = m0 + i * 16 + mrow;
        if (gm >= VM) continue;
        const unsigned int b   = (unsigned int)gm / (unsigned int)LV;
        const unsigned int pix = (unsigned int)gm - b * (unsigned int)LV;
        unsigned short* vp = v + (((size_t)(b * NH + w)) * LV + pix) * HD;
#pragma unroll
        for (int j = 0; j < 2; ++j) {
            uint2 o;
            o.x = pk2bf(acc[i][j][0] + bj[j].x, acc[i][j][1] + bj[j].y);
            o.y = pk2bf(acc[i][j][2] + bj[j].z, acc[i][j][3] + bj[j].w);
            *(uint2*)(vp + j * 16 + quad * 4) = o;
        }
    }
}

// ---------------------------------------------------------------------------
// oproj: d_out = out_head(bf16) @ op_w + op_b (f32 out).
// Same swapped-operand structure. M-tile 32, 512 threads, grid 256.
// ---------------------------------------------------------------------------
__global__ __launch_bounds__(512, 2) void oproj_mfma_kernel(
    const unsigned short* __restrict__ Ah,   // [8192][256] bf16
    const unsigned short* __restrict__ opT,  // [256][256] bf16 [n][k]
    const float* __restrict__ bias,          // [256]
    float* __restrict__ out)                 // [8192][256] f32
{
    const int tid  = threadIdx.x;
    const int w    = tid >> 6;
    const int lane = tid & 63;
    const int mrow = lane & 15;
    const int quad = lane >> 4;
    const int m0   = blockIdx.x * 32;

    bf16x8 wf[2][8];
#pragma unroll
    for (int j = 0; j < 2; ++j) {
        const int n = w * 32 + j * 16 + mrow;
#pragma unroll
        for (int kc = 0; kc < 8; ++kc)
            wf[j][kc] = *(const bf16x8*)(const void*)(opT + (size_t)n * 256 + kc * 32 + quad * 8);
    }
    float4 bj[2];
#pragma unroll
    for (int j = 0; j < 2; ++j)
        bj[j] = *(const float4*)(bias + w * 32 + j * 16 + quad * 4);

    f32x4 acc[2][2];
#pragma unroll
    for (int i = 0; i < 2; ++i)
#pragma unroll
        for (int j = 0; j < 2; ++j) acc[i][j] = (f32x4)0.f;

#pragma unroll
    for (int kc = 0; kc < 8; ++kc) {
        bf16x8 af[2];
#pragma unroll
        for (int i = 0; i < 2; ++i) {
            const int gm = m0 + i * 16 + mrow;
            af[i] = *(const bf16x8*)(const void*)(Ah + (size_t)gm * 256 + kc * 32 + quad * 8);
        }
#pragma unroll
        for (int i = 0; i < 2; ++i)
#pragma unroll
            for (int j = 0; j < 2; ++j)
                acc[i][j] = __builtin_amdgcn_mfma_f32_16x16x32_bf16(
                    wf[j][kc], af[i], acc[i][j], 0, 0, 0);
    }

#pragma unroll
    for (int i = 0; i < 2; ++i) {
        const int gm = m0 + i * 16 + mrow;
#pragma unroll
        for (int j = 0; j < 2; ++j) {
            float4 o;
            o.x = acc[i][j][0] + bj[j].x;
            o.y = acc[i][j][1] + bj[j].y;
            o.z = acc[i][j][2] + bj[j].z;
            o.w = acc[i][j][3] + bj[j].w;
            *(float4*)(out + (size_t)gm * 256 + w * 32 + j * 16 + quad * 4) = o;
        }
    }
}

// ---------------------------------------------------------------------------
// Fused so+aw projection (f32 vector sgemm). A = query [8192][256].
// Grid x: 6 column-tiles of 64 (0..3 -> so_w N=256, 4..5 -> aw_w N=128).
// ---------------------------------------------------------------------------
__global__ __launch_bounds__(256) void qproj_kernel(
    const float* __restrict__ A,
    const float* __restrict__ so_w, const float* __restrict__ so_b,
    const float* __restrict__ aw_w, const float* __restrict__ aw_b,
    float* __restrict__ so_raw, float* __restrict__ aw_raw)
{
    __shared__ float As[16][68];
    __shared__ float Ws[16][68];

    const int tid = threadIdx.x;
    const int tx = tid & 15, ty = tid >> 4;
    const int m0 = blockIdx.y * 64;
    const int n0g = blockIdx.x * 64;

    const float* W; const float* bias; float* C; int N, n0;
    if (n0g < 256) { W = so_w; bias = so_b; C = so_raw; N = 256; n0 = n0g; }
    else           { W = aw_w; bias = aw_b; C = aw_raw; N = 128; n0 = n0g - 256; }

    const int ra = tid >> 2;
    const int ka = (tid & 3) << 2;
    const int rw = tid >> 4;
    const int cw = (tid & 15) << 2;

    float acc[4][4];
#pragma unroll
    for (int i = 0; i < 4; ++i)
#pragma unroll
        for (int j = 0; j < 4; ++j) acc[i][j] = 0.f;

    for (int k0 = 0; k0 < 256; k0 += 16) {
        const float4 av = *(const float4*)(A + (size_t)(m0 + ra) * 256 + (k0 + ka));
        As[ka + 0][ra] = av.x;
        As[ka + 1][ra] = av.y;
        As[ka + 2][ra] = av.z;
        As[ka + 3][ra] = av.w;
        *(float4*)&Ws[rw][cw] =
            *(const float4*)(W + (size_t)(k0 + rw) * N + (n0 + cw));
        __syncthreads();
#pragma unroll
        for (int k = 0; k < 16; ++k) {
            const float4 a4 = *(const float4*)&As[k][ty << 2];
            const float4 b4 = *(const float4*)&Ws[k][tx << 2];
            const float aa[4] = {a4.x, a4.y, a4.z, a4.w};
            const float bb[4] = {b4.x, b4.y, b4.z, b4.w};
#pragma unroll
            for (int i = 0; i < 4; ++i)
#pragma unroll
                for (int j = 0; j < 4; ++j)
                    acc[i][j] = fmaf(aa[i], bb[j], acc[i][j]);
        }
        __syncthreads();
    }

#pragma unroll
    for (int i = 0; i < 4; ++i) {
        const int row = m0 + (ty << 2) + i;
#pragma unroll
        for (int j = 0; j < 4; ++j) {
            const int col = n0 + (tx << 2) + j;
            C[(size_t)row * N + col] = acc[i][j] + bias[col];
        }
    }
}

// ---------------------------------------------------------------------------
// Sampling with inline softmax; bf16 v in, bf16 out_head out.
// Block: 256 threads = 32 queries x 8 lanes. Grid: 2048, XCD-swizzled.
// ---------------------------------------------------------------------------
__global__ __launch_bounds__(256) void sample_kernel(
    const unsigned short* __restrict__ v,   // [B][H][LV][32] bf16
    const float* __restrict__ so_raw,       // [B*Q][256]
    const float* __restrict__ aw_raw,       // [B*Q][128] raw logits
    const float* __restrict__ refp,         // [B][Q][4][2]
    unsigned short* __restrict__ out_head)  // [B*Q][256] bf16
{
    __shared__ __align__(16) float wts[512][4];
    __shared__ __align__(16) int   offs[512][4];

    const int blk   = blockIdx.x;
    const int xcd   = blk & 7;
    const int j     = blk >> 3;
    const int bh    = xcd * 8 + (j >> 5);
    const int chunk = j & 31;
    const int h     = bh & 7;
    const int b     = bh >> 3;

    const int t = threadIdx.x;

#pragma unroll
    for (int rep = 0; rep < 2; ++rep) {
        const int s  = t + rep * 256;
        const int qq = s >> 4;
        const int pt = s & 15;
        const int l  = pt >> 2;
        const int p  = pt & 3;
        const int rq = b * LQ + chunk * 32 + qq;

        const int Wl = (l == 0) ? 100 : (l == 1) ? 50 : (l == 2) ? 25 : 13;
        const int st = (l == 0) ? 0 : (l == 1) ? 10000 : (l == 2) ? 12500 : 13125;
        const float invW = (l == 0) ? 0.01f : (l == 1) ? 0.02f : (l == 2) ? 0.04f
                                            : (1.0f / 13.0f);
        const float fw = (float)Wl;

        const float logit = aw_raw[rq * 128 + h * 16 + pt];
        float mx = logit;
#pragma unroll
        for (int d = 1; d < 16; d <<= 1) mx = fmaxf(mx, __shfl_xor(mx, d, 16));
        const float e = expf(logit - mx);
        float sm = e;
#pragma unroll
        for (int d = 1; d < 16; d <<= 1) sm += __shfl_xor(sm, d, 16);
        const float wgt = e / sm;

        const float rx = refp[((size_t)rq * 4 + l) * 2 + 0];
        const float ry = refp[((size_t)rq * 4 + l) * 2 + 1];
        const int soi  = rq * 256 + h * 32 + l * 8 + p * 2;
        const float sx = so_raw[soi];
        const float sy = so_raw[soi + 1];

        const float x = (rx + sx * invW) * fw - 0.5f;
        const float y = (ry + sy * invW) * fw - 0.5f;

        const float xf = floorf(x), yf = floorf(y);
        const int x0 = (int)xf, y0 = (int)yf;
        const float wx1 = x - xf, wx0 = 1.f - wx1;
        const float wy1 = y - yf, wy0 = 1.f - wy1;

        const float vx0 = (x0 >= 0 && x0 < Wl) ? 1.f : 0.f;
        const float vx1 = (x0 + 1 >= 0 && x0 + 1 < Wl) ? 1.f : 0.f;
        const float vy0 = (y0 >= 0 && y0 < Wl) ? 1.f : 0.f;
        const float vy1 = (y0 + 1 >= 0 && y0 + 1 < Wl) ? 1.f : 0.f;

        const int xc0 = min(max(x0, 0), Wl - 1);
        const int xc1 = min(max(x0 + 1, 0), Wl - 1);
        const int yc0 = min(max(y0, 0), Wl - 1);
        const int yc1 = min(max(y0 + 1, 0), Wl - 1);

        const int row0 = st + yc0 * Wl;
        const int row1 = st + yc1 * Wl;

        wts[s][0] = wgt * wy0 * wx0 * vy0 * vx0;
        wts[s][1] = wgt * wy0 * wx1 * vy0 * vx1;
        wts[s][2] = wgt * wy1 * wx0 * vy1 * vx0;
        wts[s][3] = wgt * wy1 * wx1 * vy1 * vx1;
        offs[s][0] = (row0 + xc0) * HD;
        offs[s][1] = (row0 + xc1) * HD;
        offs[s][2] = (row1 + xc0) * HD;
        offs[s][3] = (row1 + xc1) * HD;
    }
    __syncthreads();

    const int qq = t >> 3;
    const int ln = t & 7;
    const unsigned short* vb = v + (size_t)bh * (LV * HD) + ln * 4;

    float a0 = 0.f, a1 = 0.f, a2 = 0.f, a3 = 0.f;

#pragma unroll 4
    for (int pt = 0; pt < 16; ++pt) {
        const int s = qq * 16 + pt;
        const float4 w4 = *(const float4*)&wts[s][0];
        const int4   o4 = *(const int4*)&offs[s][0];

        const ushort4 u0 = *(const ushort4*)(vb + o4.x);
        const ushort4 u1 = *(const ushort4*)(vb + o4.y);
        const ushort4 u2 = *(const ushort4*)(vb + o4.z);
        const ushort4 u3 = *(const ushort4*)(vb + o4.w);

        a0 = fmaf(w4.x, bf2f(u0.x), a0);
        a1 = fmaf(w4.x, bf2f(u0.y), a1);
        a2 = fmaf(w4.x, bf2f(u0.z), a2);
        a3 = fmaf(w4.x, bf2f(u0.w), a3);
        a0 = fmaf(w4.y, bf2f(u1.x), a0);
        a1 = fmaf(w4.y, bf2f(u1.y), a1);
        a2 = fmaf(w4.y, bf2f(u1.z), a2);
        a3 = fmaf(w4.y, bf2f(u1.w), a3);
        a0 = fmaf(w4.z, bf2f(u2.x), a0);
        a1 = fmaf(w4.z, bf2f(u2.y), a1);
        a2 = fmaf(w4.z, bf2f(u2.z), a2);
        a3 = fmaf(w4.z, bf2f(u2.w), a3);
        a0 = fmaf(w4.w, bf2f(u3.x), a0);
        a1 = fmaf(w4.w, bf2f(u3.y), a1);
        a2 = fmaf(w4.w, bf2f(u3.z), a2);
        a3 = fmaf(w4.w, bf2f(u3.w), a3);
    }

    const int rq = b * LQ + chunk * 32 + qq;
    uint2 o;
    o.x = pk2bf(a0, a1);
    o.y = pk2bf(a2, a3);
    *(uint2*)(out_head + (size_t)rq * 256 + (h << 5) + (ln << 2)) = o;
}

// ---------------------------------------------------------------------------
extern "C" void kernel_launch(void* const* d_in, const int* in_sizes, int n_in,
                              void* d_out, int out_size, void* d_ws, size_t ws_size,
                              hipStream_t stream)
{
    const float* query = (const float*)d_in[0];
    const float* refp  = (const float*)d_in[1];
    const float* value = (const float*)d_in[2];
    const float* so_w  = (const float*)d_in[4];
    const float* so_b  = (const float*)d_in[5];
    const float* aw_w  = (const float*)d_in[6];
    const float* aw_b  = (const float*)d_in[7];
    const float* vp_w  = (const float*)d_in[8];
    const float* vp_b  = (const float*)d_in[9];
    const float* op_w  = (const float*)d_in[10];
    const float* op_b  = (const float*)d_in[11];
    float* out = (float*)d_out;

    float* ws = (float*)d_ws;
    size_t off = 0;
    unsigned short* v = (unsigned short*)(ws + off);
    off += (size_t)BSZ * NH * LV * HD / 2;
    unsigned short* wTv = (unsigned short*)(ws + off); off += 32768;
    unsigned short* wTo = (unsigned short*)(ws + off); off += 32768;
    float* so_raw = ws + off; off += (size_t)BSZ * LQ * 256;
    float* aw_raw = ws + off; off += (size_t)BSZ * LQ * 128;
    unsigned short* out_head = (unsigned short*)(ws + off);
    off += (size_t)BSZ * LQ * 256 / 2;

    // 0) transpose+convert vp_w and op_w
    wconv_kernel<<<512, 256, 0, stream>>>(vp_w, op_w, wTv, wTo);

    // 1) value projection (barrier-free MFMA) -> v [b][h][pix][c]
    vproj_mfma_kernel<<<(VM + 63) / 64, 512, 0, stream>>>(value, wTv, vp_b, v);

    // 2) fused so+aw projection
    {
        dim3 grid(6, BSZ * LQ / 64);
        qproj_kernel<<<grid, 256, 0, stream>>>(query, so_w, so_b, aw_w, aw_b,
                                               so_raw, aw_raw);
    }
    // 3) deformable sampling (inline softmax) -> out_head bf16
    sample_kernel<<<BSZ * NH * (LQ / 32), 256, 0, stream>>>(
        v, so_raw, aw_raw, refp, out_head);

    // 4) output projection (MFMA) -> d_out
    oproj_mfma_kernel<<<BSZ * LQ / 32, 512, 0, stream>>>(out_head, wTo, op_b, out);
}

// Round 5
// 271.868 us; speedup vs baseline: 1.2523x; 1.2523x over previous
//
#include <hip/hip_runtime.h>
#include <hip/hip_bf16.h>
#include <math.h>

#define BSZ 8
#define LQ  1024
#define LV  13294
#define NH  8
#define HD  32
#define VM  (BSZ * LV)   // 106352 rows of value

typedef __attribute__((ext_vector_type(8))) short bf16x8;
typedef __attribute__((ext_vector_type(4))) float f32x4;

__device__ static inline unsigned short f2bf(float f) {
    unsigned int u = __float_as_uint(f);
    unsigned int r = (u + 0x7FFFu + ((u >> 16) & 1u)) >> 16;
    return (unsigned short)r;
}
__device__ static inline float bf2f(unsigned short s) {
    return __uint_as_float(((unsigned int)s) << 16);
}
__device__ static inline unsigned int pk2bf(float a, float b) {
    __hip_bfloat162 h = __float22bfloat162_rn(make_float2(a, b));
    return *(unsigned int*)&h;
}
__device__ static inline void async_load16(const void* g, void* l) {
    __builtin_amdgcn_global_load_lds(
        (const __attribute__((address_space(1))) unsigned int*)g,
        (__attribute__((address_space(3))) unsigned int*)l, 16, 0, 0);
}

// ---------------------------------------------------------------------------
// Transpose+convert vp_w and op_w [k][n] f32 -> [n][k] bf16. Grid 512.
// ---------------------------------------------------------------------------
__global__ __launch_bounds__(256) void wconv_kernel(
    const float* __restrict__ w0, const float* __restrict__ w1,
    unsigned short* __restrict__ t0, unsigned short* __restrict__ t1)
{
    const int n = blockIdx.x & 255;
    const int k = threadIdx.x;
    if (blockIdx.x < 256) t0[n * 256 + k] = f2bf(w0[k * 256 + n]);
    else                  t1[n * 256 + k] = f2bf(w1[k * 256 + n]);
}

// ---------------------------------------------------------------------------
// vproj v5: v = value @ vp_w + vp_b -> [b][h][pix][c] bf16.
// M-tile 64, N=256 (wave w -> cols w*64..+64), K=256 in 8 BK=32 chunks,
// double-buffered. A staged f32->bf16 in-register (dbuf hides latency);
// W staged via global_load_lds 16B. Swapped MFMA operands: lane=pix,
// regs=channels -> packed 8B epilogue stores. LDS 40 KB -> 4 blocks/CU.
// ---------------------------------------------------------------------------
__global__ __launch_bounds__(256, 4) void vproj_mfma_kernel(
    const float* __restrict__ A,            // [VM][256] f32
    const unsigned short* __restrict__ wT,  // [256][256] bf16 [n][k]
    const float* __restrict__ bias,         // [256]
    unsigned short* __restrict__ v)         // [B][H][LV][32] bf16
{
    __shared__ __align__(16) unsigned short Asb[2][64 * 32];    //  8 KB
    __shared__ __align__(16) unsigned short Wsb[2][256 * 32];   // 32 KB

    const int tid  = threadIdx.x;
    const int w    = tid >> 6;
    const int lane = tid & 63;
    const int mrow = lane & 15;
    const int quad = lane >> 4;
    const int m0   = blockIdx.x * 64;

    // staging indices
    const int arow = tid >> 2;            // 0..63
    const int akof = (tid & 3) << 3;      // bf16 units 0,8,16,24
    int gmA = m0 + arow; if (gmA >= VM) gmA = VM - 1;
    const float* aptr = A + (size_t)gmA * 256 + akof;

    f32x4 acc[4][4];
#pragma unroll
    for (int i = 0; i < 4; ++i)
#pragma unroll
        for (int j = 0; j < 4; ++j) acc[i][j] = (f32x4)0.f;

#define STAGE_A(c, buf) {                                                   \
        const float* ap = aptr + (c) * 32;                                  \
        const float4 f0 = *(const float4*)ap;                               \
        const float4 f1 = *(const float4*)(ap + 4);                         \
        uint4 pk;                                                           \
        pk.x = pk2bf(f0.x, f0.y); pk.y = pk2bf(f0.z, f0.w);                 \
        pk.z = pk2bf(f1.x, f1.y); pk.w = pk2bf(f1.z, f1.w);                 \
        *(uint4*)&Asb[buf][arow * 32 + akof] = pk;                          \
    }
#define STAGE_W(c, buf) {                                                   \
        const int k0 = (c) * 32;                                            \
        _Pragma("unroll")                                                   \
        for (int i = 0; i < 4; ++i) {                                       \
            const int nbase = i * 64 + w * 16;                              \
            const unsigned short* gp = wT + (size_t)(nbase + (lane >> 2)) * 256 \
                                      + k0 + ((lane & 3) << 3);             \
            async_load16(gp, &Wsb[buf][nbase * 32]);                        \
        }                                                                   \
    }

    STAGE_A(0, 0);
    STAGE_W(0, 0);
    __syncthreads();

    for (int c = 0; c < 8; ++c) {
        const int cur = c & 1;
        if (c < 7) {
            STAGE_A(c + 1, cur ^ 1);
            STAGE_W(c + 1, cur ^ 1);
        }
        bf16x8 af[4], wfr[4];
#pragma unroll
        for (int i = 0; i < 4; ++i)
            af[i] = *(const bf16x8*)&Asb[cur][(i * 16 + mrow) * 32 + (quad << 3)];
#pragma unroll
        for (int j = 0; j < 4; ++j)
            wfr[j] = *(const bf16x8*)&Wsb[cur][(w * 64 + j * 16 + mrow) * 32 + (quad << 3)];
#pragma unroll
        for (int i = 0; i < 4; ++i)
#pragma unroll
            for (int j = 0; j < 4; ++j)
                acc[i][j] = __builtin_amdgcn_mfma_f32_16x16x32_bf16(
                    wfr[j], af[i], acc[i][j], 0, 0, 0);
        __syncthreads();
    }
#undef STAGE_A
#undef STAGE_W

    // epilogue: lane = pix (i*16+mrow), regs = channels (w*64+j*16+quad*4..+4)
    float4 bj[4];
#pragma unroll
    for (int j = 0; j < 4; ++j)
        bj[j] = *(const float4*)(bias + w * 64 + j * 16 + quad * 4);

#pragma unroll
    for (int i = 0; i < 4; ++i) {
        const int gm = m0 + i * 16 + mrow;
        if (gm >= VM) continue;
        const unsigned int b   = (unsigned int)gm / (unsigned int)LV;
        const unsigned int pix = (unsigned int)gm - b * (unsigned int)LV;
#pragma unroll
        for (int j = 0; j < 4; ++j) {
            const int ch = w * 64 + j * 16 + quad * 4;
            const int h  = ch >> 5, cc = ch & 31;
            uint2 o;
            o.x = pk2bf(acc[i][j][0] + bj[j].x, acc[i][j][1] + bj[j].y);
            o.y = pk2bf(acc[i][j][2] + bj[j].z, acc[i][j][3] + bj[j].w);
            *(uint2*)(v + (((size_t)(b * NH + h)) * LV + pix) * HD + cc) = o;
        }
    }
}

// ---------------------------------------------------------------------------
// oproj: d_out = out_head(bf16) @ op_w + op_b (f32 out). (round-4 validated)
// ---------------------------------------------------------------------------
__global__ __launch_bounds__(512, 2) void oproj_mfma_kernel(
    const unsigned short* __restrict__ Ah,   // [8192][256] bf16
    const unsigned short* __restrict__ opT,  // [256][256] bf16 [n][k]
    const float* __restrict__ bias,          // [256]
    float* __restrict__ out)                 // [8192][256] f32
{
    const int tid  = threadIdx.x;
    const int w    = tid >> 6;
    const int lane = tid & 63;
    const int mrow = lane & 15;
    const int quad = lane >> 4;
    const int m0   = blockIdx.x * 32;

    bf16x8 wf[2][8];
#pragma unroll
    for (int j = 0; j < 2; ++j) {
        const int n = w * 32 + j * 16 + mrow;
#pragma unroll
        for (int kc = 0; kc < 8; ++kc)
            wf[j][kc] = *(const bf16x8*)(const void*)(opT + (size_t)n * 256 + kc * 32 + quad * 8);
    }
    float4 bj[2];
#pragma unroll
    for (int j = 0; j < 2; ++j)
        bj[j] = *(const float4*)(bias + w * 32 + j * 16 + quad * 4);

    f32x4 acc[2][2];
#pragma unroll
    for (int i = 0; i < 2; ++i)
#pragma unroll
        for (int j = 0; j < 2; ++j) acc[i][j] = (f32x4)0.f;

#pragma unroll
    for (int kc = 0; kc < 8; ++kc) {
        bf16x8 af[2];
#pragma unroll
        for (int i = 0; i < 2; ++i) {
            const int gm = m0 + i * 16 + mrow;
            af[i] = *(const bf16x8*)(const void*)(Ah + (size_t)gm * 256 + kc * 32 + quad * 8);
        }
#pragma unroll
        for (int i = 0; i < 2; ++i)
#pragma unroll
            for (int j = 0; j < 2; ++j)
                acc[i][j] = __builtin_amdgcn_mfma_f32_16x16x32_bf16(
                    wf[j][kc], af[i], acc[i][j], 0, 0, 0);
    }

#pragma unroll
    for (int i = 0; i < 2; ++i) {
        const int gm = m0 + i * 16 + mrow;
#pragma unroll
        for (int j = 0; j < 2; ++j) {
            float4 o;
            o.x = acc[i][j][0] + bj[j].x;
            o.y = acc[i][j][1] + bj[j].y;
            o.z = acc[i][j][2] + bj[j].z;
            o.w = acc[i][j][3] + bj[j].w;
            *(float4*)(out + (size_t)gm * 256 + w * 32 + j * 16 + quad * 4) = o;
        }
    }
}

// ---------------------------------------------------------------------------
// Fused so+aw projection (f32 vector sgemm). A = query [8192][256].
// ---------------------------------------------------------------------------
__global__ __launch_bounds__(256) void qproj_kernel(
    const float* __restrict__ A,
    const float* __restrict__ so_w, const float* __restrict__ so_b,
    const float* __restrict__ aw_w, const float* __restrict__ aw_b,
    float* __restrict__ so_raw, float* __restrict__ aw_raw)
{
    __shared__ float As[16][68];
    __shared__ float Ws[16][68];

    const int tid = threadIdx.x;
    const int tx = tid & 15, ty = tid >> 4;
    const int m0 = blockIdx.y * 64;
    const int n0g = blockIdx.x * 64;

    const float* W; const float* bias; float* C; int N, n0;
    if (n0g < 256) { W = so_w; bias = so_b; C = so_raw; N = 256; n0 = n0g; }
    else           { W = aw_w; bias = aw_b; C = aw_raw; N = 128; n0 = n0g - 256; }

    const int ra = tid >> 2;
    const int ka = (tid & 3) << 2;
    const int rw = tid >> 4;
    const int cw = (tid & 15) << 2;

    float acc[4][4];
#pragma unroll
    for (int i = 0; i < 4; ++i)
#pragma unroll
        for (int j = 0; j < 4; ++j) acc[i][j] = 0.f;

    for (int k0 = 0; k0 < 256; k0 += 16) {
        const float4 av = *(const float4*)(A + (size_t)(m0 + ra) * 256 + (k0 + ka));
        As[ka + 0][ra] = av.x;
        As[ka + 1][ra] = av.y;
        As[ka + 2][ra] = av.z;
        As[ka + 3][ra] = av.w;
        *(float4*)&Ws[rw][cw] =
            *(const float4*)(W + (size_t)(k0 + rw) * N + (n0 + cw));
        __syncthreads();
#pragma unroll
        for (int k = 0; k < 16; ++k) {
            const float4 a4 = *(const float4*)&As[k][ty << 2];
            const float4 b4 = *(const float4*)&Ws[k][tx << 2];
            const float aa[4] = {a4.x, a4.y, a4.z, a4.w};
            const float bb[4] = {b4.x, b4.y, b4.z, b4.w};
#pragma unroll
            for (int i = 0; i < 4; ++i)
#pragma unroll
                for (int j = 0; j < 4; ++j)
                    acc[i][j] = fmaf(aa[i], bb[j], acc[i][j]);
        }
        __syncthreads();
    }

#pragma unroll
    for (int i = 0; i < 4; ++i) {
        const int row = m0 + (ty << 2) + i;
#pragma unroll
        for (int j = 0; j < 4; ++j) {
            const int col = n0 + (tx << 2) + j;
            C[(size_t)row * N + col] = acc[i][j] + bias[col];
        }
    }
}

// ---------------------------------------------------------------------------
// Sampling with inline softmax; bf16 v in, bf16 out_head out.
// Occupancy capped to 4 blocks/CU via dynamic LDS (static 16 KB + 24 KB dyn)
// so each XCD's co-resident gather window (~4 heads = 3.4 MB) fits its 4 MB L2.
// ---------------------------------------------------------------------------
__global__ __launch_bounds__(256) void sample_kernel(
    const unsigned short* __restrict__ v,   // [B][H][LV][32] bf16
    const float* __restrict__ so_raw,       // [B*Q][256]
    const float* __restrict__ aw_raw,       // [B*Q][128] raw logits
    const float* __restrict__ refp,         // [B][Q][4][2]
    unsigned short* __restrict__ out_head)  // [B*Q][256] bf16
{
    __shared__ __align__(16) float wts[512][4];
    __shared__ __align__(16) int   offs[512][4];
    extern __shared__ float lds_pad[];      // occupancy limiter (unused)

    const int blk   = blockIdx.x;
    const int xcd   = blk & 7;
    const int j     = blk >> 3;
    const int bh    = xcd * 8 + (j >> 5);
    const int chunk = j & 31;
    const int h     = bh & 7;
    const int b     = bh >> 3;

    const int t = threadIdx.x;

#pragma unroll
    for (int rep = 0; rep < 2; ++rep) {
        const int s  = t + rep * 256;
        const int qq = s >> 4;
        const int pt = s & 15;
        const int l  = pt >> 2;
        const int p  = pt & 3;
        const int rq = b * LQ + chunk * 32 + qq;

        const int Wl = (l == 0) ? 100 : (l == 1) ? 50 : (l == 2) ? 25 : 13;
        const int st = (l == 0) ? 0 : (l == 1) ? 10000 : (l == 2) ? 12500 : 13125;
        const float invW = (l == 0) ? 0.01f : (l == 1) ? 0.02f : (l == 2) ? 0.04f
                                            : (1.0f / 13.0f);
        const float fw = (float)Wl;

        const float logit = aw_raw[rq * 128 + h * 16 + pt];
        float mx = logit;
#pragma unroll
        for (int d = 1; d < 16; d <<= 1) mx = fmaxf(mx, __shfl_xor(mx, d, 16));
        const float e = expf(logit - mx);
        float sm = e;
#pragma unroll
        for (int d = 1; d < 16; d <<= 1) sm += __shfl_xor(sm, d, 16);
        const float wgt = e / sm;

        const float rx = refp[((size_t)rq * 4 + l) * 2 + 0];
        const float ry = refp[((size_t)rq * 4 + l) * 2 + 1];
        const int soi  = rq * 256 + h * 32 + l * 8 + p * 2;
        const float sx = so_raw[soi];
        const float sy = so_raw[soi + 1];

        const float x = (rx + sx * invW) * fw - 0.5f;
        const float y = (ry + sy * invW) * fw - 0.5f;

        const float xf = floorf(x), yf = floorf(y);
        const int x0 = (int)xf, y0 = (int)yf;
        const float wx1 = x - xf, wx0 = 1.f - wx1;
        const float wy1 = y - yf, wy0 = 1.f - wy1;

        const float vx0 = (x0 >= 0 && x0 < Wl) ? 1.f : 0.f;
        const float vx1 = (x0 + 1 >= 0 && x0 + 1 < Wl) ? 1.f : 0.f;
        const float vy0 = (y0 >= 0 && y0 < Wl) ? 1.f : 0.f;
        const float vy1 = (y0 + 1 >= 0 && y0 + 1 < Wl) ? 1.f : 0.f;

        const int xc0 = min(max(x0, 0), Wl - 1);
        const int xc1 = min(max(x0 + 1, 0), Wl - 1);
        const int yc0 = min(max(y0, 0), Wl - 1);
        const int yc1 = min(max(y0 + 1, 0), Wl - 1);

        const int row0 = st + yc0 * Wl;
        const int row1 = st + yc1 * Wl;

        wts[s][0] = wgt * wy0 * wx0 * vy0 * vx0;
        wts[s][1] = wgt * wy0 * wx1 * vy0 * vx1;
        wts[s][2] = wgt * wy1 * wx0 * vy1 * vx0;
        wts[s][3] = wgt * wy1 * wx1 * vy1 * vx1;
        offs[s][0] = (row0 + xc0) * HD;
        offs[s][1] = (row0 + xc1) * HD;
        offs[s][2] = (row1 + xc0) * HD;
        offs[s][3] = (row1 + xc1) * HD;
    }
    __syncthreads();

    const int qq = t >> 3;
    const int ln = t & 7;
    const unsigned short* vb = v + (size_t)bh * (LV * HD) + ln * 4;

    float a0 = 0.f, a1 = 0.f, a2 = 0.f, a3 = 0.f;

#pragma unroll 4
    for (int pt = 0; pt < 16; ++pt) {
        const int s = qq * 16 + pt;
        const float4 w4 = *(const float4*)&wts[s][0];
        const int4   o4 = *(const int4*)&offs[s][0];

        const ushort4 u0 = *(const ushort4*)(vb + o4.x);
        const ushort4 u1 = *(const ushort4*)(vb + o4.y);
        const ushort4 u2 = *(const ushort4*)(vb + o4.z);
        const ushort4 u3 = *(const ushort4*)(vb + o4.w);

        a0 = fmaf(w4.x, bf2f(u0.x), a0);
        a1 = fmaf(w4.x, bf2f(u0.y), a1);
        a2 = fmaf(w4.x, bf2f(u0.z), a2);
        a3 = fmaf(w4.x, bf2f(u0.w), a3);
        a0 = fmaf(w4.y, bf2f(u1.x), a0);
        a1 = fmaf(w4.y, bf2f(u1.y), a1);
        a2 = fmaf(w4.y, bf2f(u1.z), a2);
        a3 = fmaf(w4.y, bf2f(u1.w), a3);
        a0 = fmaf(w4.z, bf2f(u2.x), a0);
        a1 = fmaf(w4.z, bf2f(u2.y), a1);
        a2 = fmaf(w4.z, bf2f(u2.z), a2);
        a3 = fmaf(w4.z, bf2f(u2.w), a3);
        a0 = fmaf(w4.w, bf2f(u3.x), a0);
        a1 = fmaf(w4.w, bf2f(u3.y), a1);
        a2 = fmaf(w4.w, bf2f(u3.z), a2);
        a3 = fmaf(w4.w, bf2f(u3.w), a3);
    }

    const int rq = b * LQ + chunk * 32 + qq;
    uint2 o;
    o.x = pk2bf(a0, a1);
    o.y = pk2bf(a2, a3);
    *(uint2*)(out_head + (size_t)rq * 256 + (h << 5) + (ln << 2)) = o;
}

// ---------------------------------------------------------------------------
extern "C" void kernel_launch(void* const* d_in, const int* in_sizes, int n_in,
                              void* d_out, int out_size, void* d_ws, size_t ws_size,
                              hipStream_t stream)
{
    const float* query = (const float*)d_in[0];
    const float* refp  = (const float*)d_in[1];
    const float* value = (const float*)d_in[2];
    const float* so_w  = (const float*)d_in[4];
    const float* so_b  = (const float*)d_in[5];
    const float* aw_w  = (const float*)d_in[6];
    const float* aw_b  = (const float*)d_in[7];
    const float* vp_w  = (const float*)d_in[8];
    const float* vp_b  = (const float*)d_in[9];
    const float* op_w  = (const float*)d_in[10];
    const float* op_b  = (const float*)d_in[11];
    float* out = (float*)d_out;

    float* ws = (float*)d_ws;
    size_t off = 0;
    unsigned short* v = (unsigned short*)(ws + off);
    off += (size_t)BSZ * NH * LV * HD / 2;
    unsigned short* wTv = (unsigned short*)(ws + off); off += 32768;
    unsigned short* wTo = (unsigned short*)(ws + off); off += 32768;
    float* so_raw = ws + off; off += (size_t)BSZ * LQ * 256;
    float* aw_raw = ws + off; off += (size_t)BSZ * LQ * 128;
    unsigned short* out_head = (unsigned short*)(ws + off);
    off += (size_t)BSZ * LQ * 256 / 2;

    // 0) transpose+convert vp_w and op_w
    wconv_kernel<<<512, 256, 0, stream>>>(vp_w, op_w, wTv, wTo);

    // 1) value projection (dbuf MFMA) -> v [b][h][pix][c]
    vproj_mfma_kernel<<<(VM + 63) / 64, 256, 0, stream>>>(value, wTv, vp_b, v);

    // 2) fused so+aw projection
    {
        dim3 grid(6, BSZ * LQ / 64);
        qproj_kernel<<<grid, 256, 0, stream>>>(query, so_w, so_b, aw_w, aw_b,
                                               so_raw, aw_raw);
    }
    // 3) deformable sampling (occupancy-capped for L2 residency) -> out_head
    sample_kernel<<<BSZ * NH * (LQ / 32), 256, 24576, stream>>>(
        v, so_raw, aw_raw, refp, out_head);

    // 4) output projection (MFMA) -> d_out
    oproj_mfma_kernel<<<BSZ * LQ / 32, 512, 0, stream>>>(out_head, wTo, op_b, out);
}